// Round 12
// baseline (352.737 us; speedup 1.0000x reference)
//
#include <hip/hip_runtime.h>
#include <stdint.h>

typedef unsigned short u16;
typedef __attribute__((ext_vector_type(8))) short short8;   // 8 x bf16 (4 VGPRs)
typedef __attribute__((ext_vector_type(4))) float float4v;  // MFMA 16x16 C/D

#define MFMA16(a, b, c) __builtin_amdgcn_mfma_f32_16x16x32_bf16((a), (b), (c), 0, 0, 0)

// fold softmax scale (1/8) and log2(e) into Q so p = exp2(S) directly
#define Q_SCALE 0.18033688011112042f

// XOR-swizzled address in a 64-col u16 tile: 16B chunk index ^= row&7.
__device__ __forceinline__ int swz(int row, int col) {
  return row * 64 + (col & 7) + ((((col >> 3) ^ row) & 7) << 3);
}

// float -> bf16 (RNE)
__device__ __forceinline__ u16 f2b(float f) {
  union { float f; unsigned u; } x; x.f = f;
  unsigned r = x.u + 0x7fffu + ((x.u >> 16) & 1u);
  return (u16)(r >> 16);
}

// pack two floats to {lo,hi} bf16 pair (RNE)
__device__ __forceinline__ unsigned pack2(float a, float b) {
  return (unsigned)f2b(a) | ((unsigned)f2b(b) << 16);
}

// async global->LDS, 16B per lane; LDS dest = wave-uniform base + lane*16
__device__ __forceinline__ void load_lds_16(const void* g, void* l) {
  __builtin_amdgcn_global_load_lds((__attribute__((address_space(1))) void*)g,
                                   (__attribute__((address_space(3))) void*)l,
                                   16, 0, 0);
}

// ---------------- fp32 -> bf16 convert, all three inputs in one launch ----------------
// segments (in units of 8 floats): x 1048576 | Wa 393216 | Wp 131072 ; grid = 6144*256 exactly
__global__ __launch_bounds__(256) void cvt_all(const float* __restrict__ x,
                                               const float* __restrict__ Wa,
                                               const float* __restrict__ Wp,
                                               u16* __restrict__ xb,
                                               u16* __restrict__ Wab,
                                               u16* __restrict__ Wpb) {
  int i = blockIdx.x * 256 + threadIdx.x;
  const float* src;
  u16* dst;
  int j;
  if (i < 1048576) { src = x;  dst = xb;  j = i; }
  else if (i < 1441792) { src = Wa; dst = Wab; j = i - 1048576; }
  else { src = Wp; dst = Wpb; j = i - 1441792; }
  const float4* p = (const float4*)src + (size_t)j * 2;
  float4 a = p[0], b = p[1];
  uint4 w;
  w.x = pack2(a.x, a.y);
  w.y = pack2(a.z, a.w);
  w.z = pack2(b.x, b.y);
  w.w = pack2(b.z, b.w);
  *(uint4*)&dst[(size_t)j * 8] = w;
}

// ---------------- GEMM1: QKV projection (swizzled LDS, XCD swizzle) ----------------
// q/k blocks (bn0 < 2048): SWAPPED orientation (A=W, B=x) -> thread holds 4 consecutive
// channels d at one t -> 8B uint2 stores into QKV[which][bh][t][d] (16 stores vs 64 scalar).
// V blocks (bn0 >= 2048): original orientation -> 4 consecutive t at one d -> 8B stores
// DIRECTLY TRANSPOSED into Vt_out[bh][d][t] (replaces the transpose kernel).
__global__ __launch_bounds__(256) void gemm_qkv(const u16* __restrict__ A,
                                                const u16* __restrict__ B,
                                                const float* __restrict__ bias,
                                                u16* __restrict__ QKV,
                                                u16* __restrict__ Vt_out,
                                                int M, int N, int K) {
  __shared__ __align__(16) u16 As[128 * 64];
  __shared__ __align__(16) u16 Bs[128 * 64];
  const int tid = threadIdx.x;
  const int lane = tid & 63;
  const int wave = tid >> 6;
  const int quad = lane >> 4;
  const int l15 = lane & 15;

  // XCD-aware bijective remap (nwg % 8 == 0): XCD j serves a contiguous logical range
  const int nwg = gridDim.x * gridDim.y;
  int id = blockIdx.y * gridDim.x + blockIdx.x;
  id = (id & 7) * (nwg >> 3) + (id >> 3);
  const int bm0 = (id / gridDim.x) * 128;
  const int bn0 = (id % gridDim.x) * 128;

  const int wm = (wave & 1) * 64;
  const int wn = (wave >> 1) * 64;
  const bool qk = (bn0 < 2048);   // block-uniform (tiles never straddle the 1024/2048 bounds)

  float4v acc[4][4];
#pragma unroll
  for (int i = 0; i < 4; ++i)
#pragma unroll
    for (int j = 0; j < 4; ++j) acc[i][j] = (float4v){0.f, 0.f, 0.f, 0.f};

  // staging with swizzled SOURCE column so LDS layout is chunk^row swizzled
  const int srow = wave * 32 + (lane >> 3);
  const int scol = ((lane & 7) ^ ((lane >> 3) & 7)) * 8;

  for (int k0 = 0; k0 < K; k0 += 64) {
#pragma unroll
    for (int s = 0; s < 4; ++s) {
      const int r = s * 8;
      load_lds_16(&A[(size_t)(bm0 + srow + r) * K + k0 + scol], &As[(wave * 32 + r) * 64]);
      load_lds_16(&B[(size_t)(bn0 + srow + r) * K + k0 + scol], &Bs[(wave * 32 + r) * 64]);
    }
    __builtin_amdgcn_s_waitcnt(0);
    __syncthreads();
#pragma unroll
    for (int ks = 0; ks < 2; ++ks) {
      short8 af[4], bf[4];
#pragma unroll
      for (int t = 0; t < 4; ++t) {
        af[t] = *(const short8*)&As[swz(wm + t * 16 + l15, ks * 32 + quad * 8)];
        bf[t] = *(const short8*)&Bs[swz(wn + t * 16 + l15, ks * 32 + quad * 8)];
      }
      if (qk) {
        // acc[wt][xt]: row = W-channel, col = t
#pragma unroll
        for (int wt = 0; wt < 4; ++wt)
#pragma unroll
          for (int xt = 0; xt < 4; ++xt)
            acc[wt][xt] = MFMA16(bf[wt], af[xt], acc[wt][xt]);
      } else {
        // acc[mt][nt]: row = t, col = channel
#pragma unroll
        for (int mt = 0; mt < 4; ++mt)
#pragma unroll
          for (int nt = 0; nt < 4; ++nt)
            acc[mt][nt] = MFMA16(af[mt], bf[nt], acc[mt][nt]);
      }
    }
    __syncthreads();
  }

  if (qk) {
    const int which = bn0 >> 10;   // 0=q, 1=k (block-uniform)
    const float sc = (which == 0) ? Q_SCALE : 1.0f;
#pragma unroll
    for (int wt = 0; wt < 4; ++wt) {
      const int ch0 = bn0 + wn + wt * 16 + quad * 4;   // 4 consecutive channels
      const int h = (ch0 & 1023) >> 6;
      const int d0 = ch0 & 63;
      const float4 bsv = *(const float4*)&bias[ch0];
#pragma unroll
      for (int xt = 0; xt < 4; ++xt) {
        const int t = bm0 + wm + xt * 16 + l15;
        const int b = t >> 11;
        const int tt = t & 2047;
        uint2 w;
        w.x = pack2((acc[wt][xt][0] + bsv.x) * sc, (acc[wt][xt][1] + bsv.y) * sc);
        w.y = pack2((acc[wt][xt][2] + bsv.z) * sc, (acc[wt][xt][3] + bsv.w) * sc);
        *(uint2*)&QKV[(size_t)which * 8388608 +
                      ((size_t)(b * 16 + h) * 2048 + tt) * 64 + d0] = w;
      }
    }
  } else {
#pragma unroll
    for (int mt = 0; mt < 4; ++mt) {
      const int row0 = bm0 + wm + mt * 16 + quad * 4;
#pragma unroll
      for (int nt = 0; nt < 4; ++nt) {
        const int col = bn0 + wn + nt * 16 + l15;
        const float bs = bias[col];
        const int h = (col & 1023) >> 6;
        const int d = col & 63;
        // V transposed: vt[(bh*64 + d)*2048 + t], 4 consecutive t -> one 8B store
        const int bb = row0 >> 11;
        const int tt0 = row0 & 2047;
        uint2 w;
        w.x = pack2(acc[mt][nt][0] + bs, acc[mt][nt][1] + bs);
        w.y = pack2(acc[mt][nt][2] + bs, acc[mt][nt][3] + bs);
        *(uint2*)&Vt_out[((size_t)(bb * 16 + h) * 64 + d) * 2048 + tt0] = w;
      }
    }
  }
}

// ---------------- GEMM2: 64x128 tiles, SWAPPED orientation -> float4 stores ----------------
// C[M,N] = A[M,K] * B[N,K]^T + bias, fp32 out. acc[nt][mt]: row = out-channel, col = t;
// thread holds 4 consecutive channels at one t -> one 16B float4 store (8 stores vs 64).
__global__ __launch_bounds__(256) void gemm2_64(const u16* __restrict__ A,
                                                const u16* __restrict__ B,
                                                const float* __restrict__ bias,
                                                float* __restrict__ Cf,
                                                int M, int N, int K) {
  __shared__ __align__(16) u16 As[64 * 64];
  __shared__ __align__(16) u16 Bs[128 * 64];
  const int tid = threadIdx.x;
  const int lane = tid & 63;
  const int wave = tid >> 6;
  const int quad = lane >> 4;
  const int l15 = lane & 15;

  // XCD-aware bijective remap (nwg % 8 == 0)
  const int nwg = gridDim.x * gridDim.y;
  int id = blockIdx.y * gridDim.x + blockIdx.x;
  id = (id & 7) * (nwg >> 3) + (id >> 3);
  const int bm0 = (id / gridDim.x) * 64;
  const int bn0 = (id % gridDim.x) * 128;

  const int wm = (wave & 1) * 32;
  const int wn = (wave >> 1) * 64;

  float4v acc[4][2];
#pragma unroll
  for (int i = 0; i < 4; ++i)
#pragma unroll
    for (int j = 0; j < 2; ++j) acc[i][j] = (float4v){0.f, 0.f, 0.f, 0.f};

  const int r8 = lane >> 3;
  const int c8 = ((lane & 7) ^ r8) * 8;

  for (int k0 = 0; k0 < K; k0 += 64) {
    // As: 64 rows = 8 chunks of 8 rows; c = wave*2+p
#pragma unroll
    for (int p = 0; p < 2; ++p) {
      const int c = wave * 2 + p;
      load_lds_16(&A[(size_t)(bm0 + c * 8 + r8) * K + k0 + c8], &As[c * 512]);
    }
    // Bs: 128 rows = 16 chunks; c = wave*4+p
#pragma unroll
    for (int p = 0; p < 4; ++p) {
      const int c = wave * 4 + p;
      load_lds_16(&B[(size_t)(bn0 + c * 8 + r8) * K + k0 + c8], &Bs[c * 512]);
    }
    __builtin_amdgcn_s_waitcnt(0);
    __syncthreads();
#pragma unroll
    for (int ks = 0; ks < 2; ++ks) {
      short8 af[2], bf[4];
#pragma unroll
      for (int t = 0; t < 2; ++t)
        af[t] = *(const short8*)&As[swz(wm + t * 16 + l15, ks * 32 + quad * 8)];
#pragma unroll
      for (int t = 0; t < 4; ++t)
        bf[t] = *(const short8*)&Bs[swz(wn + t * 16 + l15, ks * 32 + quad * 8)];
#pragma unroll
      for (int nt = 0; nt < 4; ++nt)
#pragma unroll
        for (int mt = 0; mt < 2; ++mt)
          acc[nt][mt] = MFMA16(bf[nt], af[mt], acc[nt][mt]);
    }
    __syncthreads();
  }

#pragma unroll
  for (int nt = 0; nt < 4; ++nt) {
    const int ch0 = bn0 + wn + nt * 16 + quad * 4;   // 4 consecutive out channels
    const float4 bsv = *(const float4*)&bias[ch0];
#pragma unroll
    for (int mt = 0; mt < 2; ++mt) {
      const int t = bm0 + wm + mt * 16 + l15;
      float4 w;
      w.x = acc[nt][mt][0] + bsv.x;
      w.y = acc[nt][mt][1] + bsv.y;
      w.z = acc[nt][mt][2] + bsv.z;
      w.w = acc[nt][mt][3] + bsv.w;
      *(float4*)&Cf[(size_t)t * N + ch0] = w;
    }
  }
}

// ---------------- flash attention: paired q-tiles, swapped QK^T, permlane softmax, ----------------
// ---------------- K 3-buf dist-2 + V 2-buf dist-1 in LDS, counted vmcnt, rs via ones-MFMA --------
// Grid (16, 64) with XCD-bijective remap: each XCD serves 8 complete bh's (K/V L2-local).
// Block handles q-tiles {bx, 31-bx}. LDS = 24KB K-ring + 16KB V-pingpong = 40KB.
// Stage order per iter: V(st+1) THEN K(st+2); end-of-iter vmcnt(2) drains V(st+1),K(st+1),
// keeps K(st+2) in flight. Never vmcnt(0) mid-loop.
// S^T = mfma(K, Q): lane holds P[q = l15][k = nt*16 + quad*4 + i]. P -> bf16 via f2b pack;
// permlane32+16 swaps assemble PV A-fragments in-register. Row-sums via MFMA(P, ones) land in
// o's C/D layout (no VALU adds, no epilogue shuffles).
__global__ __launch_bounds__(256) void attn_kernel(const u16* __restrict__ QKV,
                                                   const u16* __restrict__ Vt_g,
                                                   u16* __restrict__ Y) {
  int id = blockIdx.y * 16 + blockIdx.x;          // 0..1023
  id = (id & 7) * 128 + (id >> 3);                // bijective XCD remap
  const int bx = id & 15;   // 0..15
  const int bh = id >> 4;   // 0..63
  const int b = bh >> 4, h = bh & 15;
  const int tid = threadIdx.x;
  const int lane = tid & 63;
  const int wave = tid >> 6;
  const int quad = lane >> 4;
  const int l15 = lane & 15;
  const int qt[2] = {bx, 31 - bx};

  const u16* Qg = QKV + (size_t)bh * 2048 * 64;
  const u16* Kg = QKV + 8388608 + (size_t)bh * 2048 * 64;
  const u16* Vg = Vt_g + (size_t)bh * 64 * 2048;   // [d][t]

  __shared__ __align__(16) u16 Ks[3][64 * 64];
  __shared__ __align__(16) u16 Vt[2][64 * 64];

  // Q fragments (B-operand: n = q = l15, k-slot = quad*8+j); Q pre-scaled by GEMM1
  short8 qf[2][2];
#pragma unroll
  for (int u = 0; u < 2; ++u)
#pragma unroll
    for (int ks = 0; ks < 2; ++ks)
      qf[u][ks] = *(const short8*)&Qg[(size_t)(qt[u] * 64 + wave * 16 + l15) * 64 + ks * 32 + quad * 8];

  float4v o[2][4];
  float4v rsacc[2];
#pragma unroll
  for (int u = 0; u < 2; ++u) {
    rsacc[u] = (float4v){0.f, 0.f, 0.f, 0.f};
#pragma unroll
    for (int i = 0; i < 4; ++i) o[u][i] = (float4v){0.f, 0.f, 0.f, 0.f};
  }

  // bf16 ones vector for row-sum MFMA
  const short8 ones8 = {0x3F80, 0x3F80, 0x3F80, 0x3F80, 0x3F80, 0x3F80, 0x3F80, 0x3F80};

  // staging: swizzle the global SOURCE column chunk; LDS dest stays lane-linear
  const int r8 = lane >> 3;
  const int c8 = ((lane & 7) ^ r8) * 8;
  auto stageK = [&](int st_, int bufi) {
#pragma unroll
    for (int p = 0; p < 2; ++p) {
      const int c = wave * 2 + p;
      load_lds_16(&Kg[(size_t)(st_ * 64 + c * 8 + r8) * 64 + c8], &Ks[bufi][c * 512]);
    }
  };
  auto stageV = [&](int st_, int bufi) {
#pragma unroll
    for (int p = 0; p < 2; ++p) {
      const int c = wave * 2 + p;
      load_lds_16(&Vg[(size_t)(c * 8 + r8) * 2048 + st_ * 64 + c8], &Vt[bufi][c * 512]);
    }
  };

  const int last = qt[1];   // >= 16 always
  // prologue (issue order oldest->newest: V0, K0, K1)
  stageV(0, 0);
  stageK(0, 0);
  stageK(1, 1);
  asm volatile("s_waitcnt vmcnt(2)" ::: "memory");   // V0,K0 complete; K1 in flight
  __builtin_amdgcn_s_barrier();

  int cur = 0;
  for (int st = 0; st <= last; ++st) {
    const int vcur = st & 1;
    // issue V BEFORE K so vmcnt(2) at iter end drains V(st+1)
    if (st + 1 <= last) stageV(st + 1, vcur ^ 1);
    const bool pfk = (st + 2 <= last);      // block-uniform
    if (pfk) {
      int nb = cur + 2; if (nb >= 3) nb -= 3;
      stageK(st + 2, nb);                   // overwrites buffer read at iter st-1 (barrier-protected)
    }
    const bool both = (st <= qt[0]);        // block-uniform

    // S^T = K Q^T for both q-tiles, sharing each kf read
    float4v s[2][4];
#pragma unroll
    for (int u = 0; u < 2; ++u)
#pragma unroll
      for (int nt = 0; nt < 4; ++nt) s[u][nt] = (float4v){0.f, 0.f, 0.f, 0.f};
    __builtin_amdgcn_s_setprio(1);
#pragma unroll
    for (int ks = 0; ks < 2; ++ks)
#pragma unroll
      for (int nt = 0; nt < 4; ++nt) {
        const short8 kf = *(const short8*)&Ks[cur][swz(nt * 16 + l15, ks * 32 + quad * 8)];
        s[1][nt] = MFMA16(kf, qf[1][ks], s[1][nt]);
        if (both) s[0][nt] = MFMA16(kf, qf[0][ks], s[0][nt]);
      }
    __builtin_amdgcn_s_setprio(0);

    // softmax per q-tile -> PV A-fragments (pure VALU, no DS) + row-sum MFMA
    short8 af[2][2];
#pragma unroll
    for (int u = 0; u < 2; ++u) {
      if (u == 0 && !both) continue;

      if (st == qt[u]) {   // diagonal tile: causal mask (block-uniform branch)
        const int qrow = wave * 16 + l15;            // q local
        const int kb = quad * 4;                     // k local base
#pragma unroll
        for (int nt = 0; nt < 4; ++nt)
#pragma unroll
          for (int i = 0; i < 4; ++i)
            if (kb + nt * 16 + i > qrow) s[u][nt][i] = -1e30f;
      }

      // p = exp2(s); pack pairs to bf16 (f2b RNE)
      unsigned pkx[4], pky[4];
#pragma unroll
      for (int nt = 0; nt < 4; ++nt) {
        const float p0 = __builtin_amdgcn_exp2f(s[u][nt][0]);
        const float p1 = __builtin_amdgcn_exp2f(s[u][nt][1]);
        const float p2 = __builtin_amdgcn_exp2f(s[u][nt][2]);
        const float p3 = __builtin_amdgcn_exp2f(s[u][nt][3]);
        pkx[nt] = pack2(p0, p1);
        pky[nt] = pack2(p2, p3);
      }

      // redistribute in-register: per ks, swap32 then swap16 on (pk[2ks], pk[2ks+1])
#pragma unroll
      for (int ks = 0; ks < 2; ++ks) {
        unsigned ax = pkx[2 * ks], bx2 = pkx[2 * ks + 1];
        unsigned ay = pky[2 * ks], by2 = pky[2 * ks + 1];
        asm("v_permlane32_swap_b32 %0, %1" : "+v"(ax), "+v"(bx2));
        asm("v_permlane16_swap_b32 %0, %1" : "+v"(ax), "+v"(bx2));
        asm("v_permlane32_swap_b32 %0, %1" : "+v"(ay), "+v"(by2));
        asm("v_permlane16_swap_b32 %0, %1" : "+v"(ay), "+v"(by2));
        uint4 w;
        w.x = ax; w.y = ay; w.z = bx2; w.w = by2;
        af[u][ks] = *(const short8*)&w;
        // row-sum in o's C/D layout: rsacc[u][i] = sum_k P[q = quad*4+i][k]
        rsacc[u] = MFMA16(af[u][ks], ones8, rsacc[u]);
      }
    }

    // O += P V, vf from LDS ping-pong, shared across both q-tiles
    __builtin_amdgcn_s_setprio(1);
#pragma unroll
    for (int ks = 0; ks < 2; ++ks)
#pragma unroll
      for (int dt = 0; dt < 4; ++dt) {
        const short8 vf = *(const short8*)&Vt[vcur][swz(dt * 16 + l15, ks * 32 + quad * 8)];
        o[1][dt] = MFMA16(af[1][ks], vf, o[1][dt]);
        if (both) o[0][dt] = MFMA16(af[0][ks], vf, o[0][dt]);
      }
    __builtin_amdgcn_s_setprio(0);

    // counted wait: V(st+1), K(st+1) complete; K(st+2)'s 2 loads stay in flight
    if (pfk) asm volatile("s_waitcnt vmcnt(2)" ::: "memory");
    else     asm volatile("s_waitcnt vmcnt(0)" ::: "memory");
    __builtin_amdgcn_s_barrier();

    ++cur; if (cur >= 3) cur = 0;
  }

  // epilogue: rsacc already in o's layout -> normalize directly, write Y[b][t][h*64+d]
#pragma unroll
  for (int u = 0; u < 2; ++u) {
    float linv[4];
#pragma unroll
    for (int i = 0; i < 4; ++i) linv[i] = 1.0f / rsacc[u][i];
#pragma unroll
    for (int dt = 0; dt < 4; ++dt)
#pragma unroll
      for (int i = 0; i < 4; ++i) {
        const float v = o[u][dt][i] * linv[i];
        const int t = qt[u] * 64 + wave * 16 + quad * 4 + i;
        Y[((size_t)b * 2048 + t) * 1024 + h * 64 + dt * 16 + l15] = f2b(v);
      }
  }
}

// ---------------- launch ----------------
extern "C" void kernel_launch(void* const* d_in, const int* in_sizes, int n_in,
                              void* d_out, int out_size, void* d_ws, size_t ws_size,
                              hipStream_t stream) {
  const float* x  = (const float*)d_in[0];   // [4,2048,1024]
  const float* Wa = (const float*)d_in[1];   // [3072,1024]
  const float* ba = (const float*)d_in[2];   // [3072]
  const float* Wp = (const float*)d_in[3];   // [1024,1024]
  const float* bp = (const float*)d_in[4];   // [1024]
  float* out = (float*)d_out;                // [4,2048,1024] fp32

  u16* xb  = (u16*)d_ws;                  // 8388608  (reused as Y after GEMM1)
  u16* Wab = xb + 8388608;                // 3145728
  u16* Wpb = Wab + 3145728;               // 1048576
  u16* qkv = Wpb + 1048576;               // q,k used; v slot unused (V goes transposed to vt)
  u16* y   = xb;                          // alias: x consumed by GEMM1 before attn writes y
  u16* vt  = (u16*)d_out;                 // 16.8MB scratch in d_out (GEMM2 overwrites later)

  cvt_all<<<6144, 256, 0, stream>>>(x, Wa, Wp, xb, Wab, Wpb);

  gemm_qkv<<<dim3(24, 64), 256, 0, stream>>>(xb, Wab, ba, qkv, vt, 8192, 3072, 1024);
  attn_kernel<<<dim3(16, 64), 256, 0, stream>>>(qkv, vt, y);
  gemm2_64<<<dim3(8, 128), 256, 0, stream>>>(y, Wpb, bp, out, 8192, 1024, 1024);
}

// Round 13
// 271.431 us; speedup vs baseline: 1.2995x; 1.2995x over previous
//
#include <hip/hip_runtime.h>
#include <stdint.h>

typedef unsigned short u16;
typedef __attribute__((ext_vector_type(8))) short short8;   // 8 x bf16 (4 VGPRs)
typedef __attribute__((ext_vector_type(4))) float float4v;  // MFMA 16x16 C/D

#define MFMA16(a, b, c) __builtin_amdgcn_mfma_f32_16x16x32_bf16((a), (b), (c), 0, 0, 0)

// fold softmax scale (1/8) and log2(e) into Q so p = exp2(S) directly
#define Q_SCALE 0.18033688011112042f

// XOR-swizzled address in a 64-col u16 tile: 16B chunk index ^= row&7.
__device__ __forceinline__ int swz(int row, int col) {
  return row * 64 + (col & 7) + ((((col >> 3) ^ row) & 7) << 3);
}

// float -> bf16 (RNE)
__device__ __forceinline__ u16 f2b(float f) {
  union { float f; unsigned u; } x; x.f = f;
  unsigned r = x.u + 0x7fffu + ((x.u >> 16) & 1u);
  return (u16)(r >> 16);
}

// pack two floats to {lo,hi} bf16 pair (RNE)
__device__ __forceinline__ unsigned pack2(float a, float b) {
  return (unsigned)f2b(a) | ((unsigned)f2b(b) << 16);
}

// async global->LDS, 16B per lane; LDS dest = wave-uniform base + lane*16
__device__ __forceinline__ void load_lds_16(const void* g, void* l) {
  __builtin_amdgcn_global_load_lds((__attribute__((address_space(1))) void*)g,
                                   (__attribute__((address_space(3))) void*)l,
                                   16, 0, 0);
}

// ---------------- fp32 -> bf16 convert, all three inputs in one launch ----------------
// segments (in units of 8 floats): x 1048576 | Wa 393216 | Wp 131072 ; grid = 6144*256 exactly
__global__ __launch_bounds__(256) void cvt_all(const float* __restrict__ x,
                                               const float* __restrict__ Wa,
                                               const float* __restrict__ Wp,
                                               u16* __restrict__ xb,
                                               u16* __restrict__ Wab,
                                               u16* __restrict__ Wpb) {
  int i = blockIdx.x * 256 + threadIdx.x;
  const float* src;
  u16* dst;
  int j;
  if (i < 1048576) { src = x;  dst = xb;  j = i; }
  else if (i < 1441792) { src = Wa; dst = Wab; j = i - 1048576; }
  else { src = Wp; dst = Wpb; j = i - 1441792; }
  const float4* p = (const float4*)src + (size_t)j * 2;
  float4 a = p[0], b = p[1];
  uint4 w;
  w.x = pack2(a.x, a.y);
  w.y = pack2(a.z, a.w);
  w.z = pack2(b.x, b.y);
  w.w = pack2(b.z, b.w);
  *(uint4*)&dst[(size_t)j * 8] = w;
}

// ---------------- GEMM1: QKV projection (swizzled LDS, XCD swizzle) ----------------
// ROUND-10 VERSION (measured-good): single orientation acc[mt][nt] (row=t, col=channel).
// q/k written scalar bf16 to QKV[0..1]; V written DIRECTLY TRANSPOSED to Vt_out[bh][d][t]
// (4 consecutive t at one d = one 8B store; replaces the transpose kernel).
// NOTE r12 lesson: dual-orientation if(qk) in the K-loop -> 132 VGPR, occupancy 11%, +50us.
__global__ __launch_bounds__(256) void gemm_qkv(const u16* __restrict__ A,
                                                const u16* __restrict__ B,
                                                const float* __restrict__ bias,
                                                u16* __restrict__ QKV,
                                                u16* __restrict__ Vt_out,
                                                int M, int N, int K) {
  __shared__ __align__(16) u16 As[128 * 64];
  __shared__ __align__(16) u16 Bs[128 * 64];
  const int tid = threadIdx.x;
  const int lane = tid & 63;
  const int wave = tid >> 6;
  const int quad = lane >> 4;
  const int l15 = lane & 15;

  // XCD-aware bijective remap (nwg % 8 == 0): XCD j serves a contiguous logical range
  const int nwg = gridDim.x * gridDim.y;
  int id = blockIdx.y * gridDim.x + blockIdx.x;
  id = (id & 7) * (nwg >> 3) + (id >> 3);
  const int bm0 = (id / gridDim.x) * 128;
  const int bn0 = (id % gridDim.x) * 128;

  const int wm = (wave & 1) * 64;
  const int wn = (wave >> 1) * 64;

  float4v acc[4][4];
#pragma unroll
  for (int i = 0; i < 4; ++i)
#pragma unroll
    for (int j = 0; j < 4; ++j) acc[i][j] = (float4v){0.f, 0.f, 0.f, 0.f};

  // staging with swizzled SOURCE column so LDS layout is chunk^row swizzled
  const int srow = wave * 32 + (lane >> 3);
  const int scol = ((lane & 7) ^ ((lane >> 3) & 7)) * 8;

  for (int k0 = 0; k0 < K; k0 += 64) {
#pragma unroll
    for (int s = 0; s < 4; ++s) {
      const int r = s * 8;
      load_lds_16(&A[(size_t)(bm0 + srow + r) * K + k0 + scol], &As[(wave * 32 + r) * 64]);
      load_lds_16(&B[(size_t)(bn0 + srow + r) * K + k0 + scol], &Bs[(wave * 32 + r) * 64]);
    }
    __builtin_amdgcn_s_waitcnt(0);
    __syncthreads();
#pragma unroll
    for (int ks = 0; ks < 2; ++ks) {
      short8 af[4], bf[4];
#pragma unroll
      for (int t = 0; t < 4; ++t) {
        af[t] = *(const short8*)&As[swz(wm + t * 16 + l15, ks * 32 + quad * 8)];
        bf[t] = *(const short8*)&Bs[swz(wn + t * 16 + l15, ks * 32 + quad * 8)];
      }
#pragma unroll
      for (int mt = 0; mt < 4; ++mt)
#pragma unroll
        for (int nt = 0; nt < 4; ++nt)
          acc[mt][nt] = MFMA16(af[mt], bf[nt], acc[mt][nt]);
    }
    __syncthreads();
  }

#pragma unroll
  for (int mt = 0; mt < 4; ++mt) {
    const int row0 = bm0 + wm + mt * 16 + quad * 4;
#pragma unroll
    for (int nt = 0; nt < 4; ++nt) {
      const int col = bn0 + wn + nt * 16 + l15;
      const float bs = bias[col];
      const int which = col >> 10;   // 0=q 1=k 2=v
      const int rem = col & 1023;
      const int h = rem >> 6;
      const int d = rem & 63;
      if (which == 2) {
        // V transposed: vt[(bh*64 + d)*2048 + t], 4 consecutive t -> one 8B store
        const int bb = row0 >> 11;
        const int tt0 = row0 & 2047;
        uint2 w;
        w.x = pack2(acc[mt][nt][0] + bs, acc[mt][nt][1] + bs);
        w.y = pack2(acc[mt][nt][2] + bs, acc[mt][nt][3] + bs);
        *(uint2*)&Vt_out[((size_t)(bb * 16 + h) * 64 + d) * 2048 + tt0] = w;
      } else {
        const float sc = (which == 0) ? Q_SCALE : 1.0f;  // pre-scale q for exp2 softmax
#pragma unroll
        for (int i = 0; i < 4; ++i) {
          const int t = row0 + i;
          const int b = t >> 11;
          const int tt = t & 2047;
          QKV[(size_t)which * 8388608 +
              ((size_t)(b * 16 + h) * 2048 + tt) * 64 + d] = f2b((acc[mt][nt][i] + bs) * sc);
        }
      }
    }
  }
}

// ---------------- GEMM2: 64x128 tiles, SWAPPED orientation -> float4 stores ----------------
// C[M,N] = A[M,K] * B[N,K]^T + bias, fp32 out. acc[nt][mt]: row = out-channel, col = t;
// thread holds 4 consecutive channels at one t -> one 16B float4 store (8 stores vs 64).
// Single-path (no orientation branch) so register pressure stays flat (r12 lesson).
__global__ __launch_bounds__(256) void gemm2_64(const u16* __restrict__ A,
                                                const u16* __restrict__ B,
                                                const float* __restrict__ bias,
                                                float* __restrict__ Cf,
                                                int M, int N, int K) {
  __shared__ __align__(16) u16 As[64 * 64];
  __shared__ __align__(16) u16 Bs[128 * 64];
  const int tid = threadIdx.x;
  const int lane = tid & 63;
  const int wave = tid >> 6;
  const int quad = lane >> 4;
  const int l15 = lane & 15;

  // XCD-aware bijective remap (nwg % 8 == 0)
  const int nwg = gridDim.x * gridDim.y;
  int id = blockIdx.y * gridDim.x + blockIdx.x;
  id = (id & 7) * (nwg >> 3) + (id >> 3);
  const int bm0 = (id / gridDim.x) * 64;
  const int bn0 = (id % gridDim.x) * 128;

  const int wm = (wave & 1) * 32;
  const int wn = (wave >> 1) * 64;

  float4v acc[4][2];
#pragma unroll
  for (int i = 0; i < 4; ++i)
#pragma unroll
    for (int j = 0; j < 2; ++j) acc[i][j] = (float4v){0.f, 0.f, 0.f, 0.f};

  const int r8 = lane >> 3;
  const int c8 = ((lane & 7) ^ r8) * 8;

  for (int k0 = 0; k0 < K; k0 += 64) {
    // As: 64 rows = 8 chunks of 8 rows; c = wave*2+p
#pragma unroll
    for (int p = 0; p < 2; ++p) {
      const int c = wave * 2 + p;
      load_lds_16(&A[(size_t)(bm0 + c * 8 + r8) * K + k0 + c8], &As[c * 512]);
    }
    // Bs: 128 rows = 16 chunks; c = wave*4+p
#pragma unroll
    for (int p = 0; p < 4; ++p) {
      const int c = wave * 4 + p;
      load_lds_16(&B[(size_t)(bn0 + c * 8 + r8) * K + k0 + c8], &Bs[c * 512]);
    }
    __builtin_amdgcn_s_waitcnt(0);
    __syncthreads();
#pragma unroll
    for (int ks = 0; ks < 2; ++ks) {
      short8 af[2], bf[4];
#pragma unroll
      for (int t = 0; t < 2; ++t)
        af[t] = *(const short8*)&As[swz(wm + t * 16 + l15, ks * 32 + quad * 8)];
#pragma unroll
      for (int t = 0; t < 4; ++t)
        bf[t] = *(const short8*)&Bs[swz(wn + t * 16 + l15, ks * 32 + quad * 8)];
#pragma unroll
      for (int nt = 0; nt < 4; ++nt)
#pragma unroll
        for (int mt = 0; mt < 2; ++mt)
          acc[nt][mt] = MFMA16(bf[nt], af[mt], acc[nt][mt]);
    }
    __syncthreads();
  }

#pragma unroll
  for (int nt = 0; nt < 4; ++nt) {
    const int ch0 = bn0 + wn + nt * 16 + quad * 4;   // 4 consecutive out channels
    const float4 bsv = *(const float4*)&bias[ch0];
#pragma unroll
    for (int mt = 0; mt < 2; ++mt) {
      const int t = bm0 + wm + mt * 16 + l15;
      float4 w;
      w.x = acc[nt][mt][0] + bsv.x;
      w.y = acc[nt][mt][1] + bsv.y;
      w.z = acc[nt][mt][2] + bsv.z;
      w.w = acc[nt][mt][3] + bsv.w;
      *(float4*)&Cf[(size_t)t * N + ch0] = w;
    }
  }
}

// ---------------- flash attention: paired q-tiles, swapped QK^T, permlane softmax, ----------------
// ---------------- K 3-buf dist-2 + V 2-buf dist-1 in LDS, counted vmcnt, rs via ones-MFMA --------
// Grid (16, 64) with XCD-bijective remap: each XCD serves 8 complete bh's (K/V L2-local).
// Block handles q-tiles {bx, 31-bx}. LDS = 24KB K-ring + 16KB V-pingpong = 40KB.
// Stage order per iter: V(st+1) THEN K(st+2); end-of-iter vmcnt(2) drains V(st+1),K(st+1),
// keeps K(st+2) in flight. Never vmcnt(0) mid-loop.
// S^T = mfma(K, Q): lane holds P[q = l15][k = nt*16 + quad*4 + i]. P -> bf16 via f2b pack;
// permlane32+16 swaps assemble PV A-fragments in-register. Row-sums via MFMA(P, ones) land in
// o's C/D layout (no VALU adds, no epilogue shuffles).
__global__ __launch_bounds__(256) void attn_kernel(const u16* __restrict__ QKV,
                                                   const u16* __restrict__ Vt_g,
                                                   u16* __restrict__ Y) {
  int id = blockIdx.y * 16 + blockIdx.x;          // 0..1023
  id = (id & 7) * 128 + (id >> 3);                // bijective XCD remap
  const int bx = id & 15;   // 0..15
  const int bh = id >> 4;   // 0..63
  const int b = bh >> 4, h = bh & 15;
  const int tid = threadIdx.x;
  const int lane = tid & 63;
  const int wave = tid >> 6;
  const int quad = lane >> 4;
  const int l15 = lane & 15;
  const int qt[2] = {bx, 31 - bx};

  const u16* Qg = QKV + (size_t)bh * 2048 * 64;
  const u16* Kg = QKV + 8388608 + (size_t)bh * 2048 * 64;
  const u16* Vg = Vt_g + (size_t)bh * 64 * 2048;   // [d][t]

  __shared__ __align__(16) u16 Ks[3][64 * 64];
  __shared__ __align__(16) u16 Vt[2][64 * 64];

  // Q fragments (B-operand: n = q = l15, k-slot = quad*8+j); Q pre-scaled by GEMM1
  short8 qf[2][2];
#pragma unroll
  for (int u = 0; u < 2; ++u)
#pragma unroll
    for (int ks = 0; ks < 2; ++ks)
      qf[u][ks] = *(const short8*)&Qg[(size_t)(qt[u] * 64 + wave * 16 + l15) * 64 + ks * 32 + quad * 8];

  float4v o[2][4];
  float4v rsacc[2];
#pragma unroll
  for (int u = 0; u < 2; ++u) {
    rsacc[u] = (float4v){0.f, 0.f, 0.f, 0.f};
#pragma unroll
    for (int i = 0; i < 4; ++i) o[u][i] = (float4v){0.f, 0.f, 0.f, 0.f};
  }

  // bf16 ones vector for row-sum MFMA
  const short8 ones8 = {0x3F80, 0x3F80, 0x3F80, 0x3F80, 0x3F80, 0x3F80, 0x3F80, 0x3F80};

  // staging: swizzle the global SOURCE column chunk; LDS dest stays lane-linear
  const int r8 = lane >> 3;
  const int c8 = ((lane & 7) ^ r8) * 8;
  auto stageK = [&](int st_, int bufi) {
#pragma unroll
    for (int p = 0; p < 2; ++p) {
      const int c = wave * 2 + p;
      load_lds_16(&Kg[(size_t)(st_ * 64 + c * 8 + r8) * 64 + c8], &Ks[bufi][c * 512]);
    }
  };
  auto stageV = [&](int st_, int bufi) {
#pragma unroll
    for (int p = 0; p < 2; ++p) {
      const int c = wave * 2 + p;
      load_lds_16(&Vg[(size_t)(c * 8 + r8) * 2048 + st_ * 64 + c8], &Vt[bufi][c * 512]);
    }
  };

  const int last = qt[1];   // >= 16 always
  // prologue (issue order oldest->newest: V0, K0, K1)
  stageV(0, 0);
  stageK(0, 0);
  stageK(1, 1);
  asm volatile("s_waitcnt vmcnt(2)" ::: "memory");   // V0,K0 complete; K1 in flight
  __builtin_amdgcn_s_barrier();

  int cur = 0;
  for (int st = 0; st <= last; ++st) {
    const int vcur = st & 1;
    // issue V BEFORE K so vmcnt(2) at iter end drains V(st+1)
    if (st + 1 <= last) stageV(st + 1, vcur ^ 1);
    const bool pfk = (st + 2 <= last);      // block-uniform
    if (pfk) {
      int nb = cur + 2; if (nb >= 3) nb -= 3;
      stageK(st + 2, nb);                   // overwrites buffer read at iter st-1 (barrier-protected)
    }
    const bool both = (st <= qt[0]);        // block-uniform

    // S^T = K Q^T for both q-tiles, sharing each kf read
    float4v s[2][4];
#pragma unroll
    for (int u = 0; u < 2; ++u)
#pragma unroll
      for (int nt = 0; nt < 4; ++nt) s[u][nt] = (float4v){0.f, 0.f, 0.f, 0.f};
    __builtin_amdgcn_s_setprio(1);
#pragma unroll
    for (int ks = 0; ks < 2; ++ks)
#pragma unroll
      for (int nt = 0; nt < 4; ++nt) {
        const short8 kf = *(const short8*)&Ks[cur][swz(nt * 16 + l15, ks * 32 + quad * 8)];
        s[1][nt] = MFMA16(kf, qf[1][ks], s[1][nt]);
        if (both) s[0][nt] = MFMA16(kf, qf[0][ks], s[0][nt]);
      }
    __builtin_amdgcn_s_setprio(0);

    // softmax per q-tile -> PV A-fragments (pure VALU, no DS) + row-sum MFMA
    short8 af[2][2];
#pragma unroll
    for (int u = 0; u < 2; ++u) {
      if (u == 0 && !both) continue;

      if (st == qt[u]) {   // diagonal tile: causal mask (block-uniform branch)
        const int qrow = wave * 16 + l15;            // q local
        const int kb = quad * 4;                     // k local base
#pragma unroll
        for (int nt = 0; nt < 4; ++nt)
#pragma unroll
          for (int i = 0; i < 4; ++i)
            if (kb + nt * 16 + i > qrow) s[u][nt][i] = -1e30f;
      }

      // p = exp2(s); pack pairs to bf16 (f2b RNE)
      unsigned pkx[4], pky[4];
#pragma unroll
      for (int nt = 0; nt < 4; ++nt) {
        const float p0 = __builtin_amdgcn_exp2f(s[u][nt][0]);
        const float p1 = __builtin_amdgcn_exp2f(s[u][nt][1]);
        const float p2 = __builtin_amdgcn_exp2f(s[u][nt][2]);
        const float p3 = __builtin_amdgcn_exp2f(s[u][nt][3]);
        pkx[nt] = pack2(p0, p1);
        pky[nt] = pack2(p2, p3);
      }

      // redistribute in-register: per ks, swap32 then swap16 on (pk[2ks], pk[2ks+1])
#pragma unroll
      for (int ks = 0; ks < 2; ++ks) {
        unsigned ax = pkx[2 * ks], bx2 = pkx[2 * ks + 1];
        unsigned ay = pky[2 * ks], by2 = pky[2 * ks + 1];
        asm("v_permlane32_swap_b32 %0, %1" : "+v"(ax), "+v"(bx2));
        asm("v_permlane16_swap_b32 %0, %1" : "+v"(ax), "+v"(bx2));
        asm("v_permlane32_swap_b32 %0, %1" : "+v"(ay), "+v"(by2));
        asm("v_permlane16_swap_b32 %0, %1" : "+v"(ay), "+v"(by2));
        uint4 w;
        w.x = ax; w.y = ay; w.z = bx2; w.w = by2;
        af[u][ks] = *(const short8*)&w;
        // row-sum in o's C/D layout: rsacc[u][i] = sum_k P[q = quad*4+i][k]
        rsacc[u] = MFMA16(af[u][ks], ones8, rsacc[u]);
      }
    }

    // O += P V, vf from LDS ping-pong, shared across both q-tiles
    __builtin_amdgcn_s_setprio(1);
#pragma unroll
    for (int ks = 0; ks < 2; ++ks)
#pragma unroll
      for (int dt = 0; dt < 4; ++dt) {
        const short8 vf = *(const short8*)&Vt[vcur][swz(dt * 16 + l15, ks * 32 + quad * 8)];
        o[1][dt] = MFMA16(af[1][ks], vf, o[1][dt]);
        if (both) o[0][dt] = MFMA16(af[0][ks], vf, o[0][dt]);
      }
    __builtin_amdgcn_s_setprio(0);

    // counted wait: V(st+1), K(st+1) complete; K(st+2)'s 2 loads stay in flight
    if (pfk) asm volatile("s_waitcnt vmcnt(2)" ::: "memory");
    else     asm volatile("s_waitcnt vmcnt(0)" ::: "memory");
    __builtin_amdgcn_s_barrier();

    ++cur; if (cur >= 3) cur = 0;
  }

  // epilogue: rsacc already in o's layout -> normalize directly, write Y[b][t][h*64+d]
#pragma unroll
  for (int u = 0; u < 2; ++u) {
    float linv[4];
#pragma unroll
    for (int i = 0; i < 4; ++i) linv[i] = 1.0f / rsacc[u][i];
#pragma unroll
    for (int dt = 0; dt < 4; ++dt)
#pragma unroll
      for (int i = 0; i < 4; ++i) {
        const float v = o[u][dt][i] * linv[i];
        const int t = qt[u] * 64 + wave * 16 + quad * 4 + i;
        Y[((size_t)b * 2048 + t) * 1024 + h * 64 + dt * 16 + l15] = f2b(v);
      }
  }
}

// ---------------- launch ----------------
extern "C" void kernel_launch(void* const* d_in, const int* in_sizes, int n_in,
                              void* d_out, int out_size, void* d_ws, size_t ws_size,
                              hipStream_t stream) {
  const float* x  = (const float*)d_in[0];   // [4,2048,1024]
  const float* Wa = (const float*)d_in[1];   // [3072,1024]
  const float* ba = (const float*)d_in[2];   // [3072]
  const float* Wp = (const float*)d_in[3];   // [1024,1024]
  const float* bp = (const float*)d_in[4];   // [1024]
  float* out = (float*)d_out;                // [4,2048,1024] fp32

  u16* xb  = (u16*)d_ws;                  // 8388608  (reused as Y after GEMM1)
  u16* Wab = xb + 8388608;                // 3145728
  u16* Wpb = Wab + 3145728;               // 1048576
  u16* qkv = Wpb + 1048576;               // q,k used; v slot unused (V goes transposed to vt)
  u16* y   = xb;                          // alias: x consumed by GEMM1 before attn writes y
  u16* vt  = (u16*)d_out;                 // 16.8MB scratch in d_out (GEMM2 overwrites later)

  cvt_all<<<6144, 256, 0, stream>>>(x, Wa, Wp, xb, Wab, Wpb);

  gemm_qkv<<<dim3(24, 64), 256, 0, stream>>>(xb, Wab, ba, qkv, vt, 8192, 3072, 1024);
  attn_kernel<<<dim3(16, 64), 256, 0, stream>>>(qkv, vt, y);
  gemm2_64<<<dim3(8, 128), 256, 0, stream>>>(y, Wpb, bp, out, 8192, 1024, 1024);
}

// Round 14
// 271.018 us; speedup vs baseline: 1.3015x; 1.0015x over previous
//
#include <hip/hip_runtime.h>
#include <stdint.h>

typedef unsigned short u16;
typedef __attribute__((ext_vector_type(8))) short short8;   // 8 x bf16 (4 VGPRs)
typedef __attribute__((ext_vector_type(4))) float float4v;  // MFMA 16x16 C/D

#define MFMA16(a, b, c) __builtin_amdgcn_mfma_f32_16x16x32_bf16((a), (b), (c), 0, 0, 0)

// fold softmax scale (1/8) and log2(e) into Q so p = exp2(S) directly
#define Q_SCALE 0.18033688011112042f

// XOR-swizzled address in a 64-col u16 tile: 16B chunk index ^= row&7.
__device__ __forceinline__ int swz(int row, int col) {
  return row * 64 + (col & 7) + ((((col >> 3) ^ row) & 7) << 3);
}

// float -> bf16 (RNE)
__device__ __forceinline__ u16 f2b(float f) {
  union { float f; unsigned u; } x; x.f = f;
  unsigned r = x.u + 0x7fffu + ((x.u >> 16) & 1u);
  return (u16)(r >> 16);
}

// pack two floats to {lo,hi} bf16 pair (RNE)
__device__ __forceinline__ unsigned pack2(float a, float b) {
  return (unsigned)f2b(a) | ((unsigned)f2b(b) << 16);
}

// pack two floats to {lo,hi} bf16 pair, round-half-UP (5 VALU ops vs ~12 for RNE).
// Differs from RNE only on exact ties (low16 == 0x8000) — one bf16 ulp, rare.
// Used ONLY for softmax P values (threshold headroom 3x); epilogues keep RNE.
__device__ __forceinline__ unsigned pack2h(float a, float b) {
  union { float f; unsigned u; } x, y; x.f = a; y.f = b;
  return ((x.u + 0x8000u) >> 16) | ((y.u + 0x8000u) & 0xFFFF0000u);
}

// async global->LDS, 16B per lane; LDS dest = wave-uniform base + lane*16
__device__ __forceinline__ void load_lds_16(const void* g, void* l) {
  __builtin_amdgcn_global_load_lds((__attribute__((address_space(1))) void*)g,
                                   (__attribute__((address_space(3))) void*)l,
                                   16, 0, 0);
}

// ---------------- fp32 -> bf16 convert, all three inputs in one launch ----------------
// segments (in units of 8 floats): x 1048576 | Wa 393216 | Wp 131072 ; grid = 6144*256 exactly
__global__ __launch_bounds__(256) void cvt_all(const float* __restrict__ x,
                                               const float* __restrict__ Wa,
                                               const float* __restrict__ Wp,
                                               u16* __restrict__ xb,
                                               u16* __restrict__ Wab,
                                               u16* __restrict__ Wpb) {
  int i = blockIdx.x * 256 + threadIdx.x;
  const float* src;
  u16* dst;
  int j;
  if (i < 1048576) { src = x;  dst = xb;  j = i; }
  else if (i < 1441792) { src = Wa; dst = Wab; j = i - 1048576; }
  else { src = Wp; dst = Wpb; j = i - 1441792; }
  const float4* p = (const float4*)src + (size_t)j * 2;
  float4 a = p[0], b = p[1];
  uint4 w;
  w.x = pack2(a.x, a.y);
  w.y = pack2(a.z, a.w);
  w.z = pack2(b.x, b.y);
  w.w = pack2(b.z, b.w);
  *(uint4*)&dst[(size_t)j * 8] = w;
}

// ---------------- GEMM1: QKV projection (swizzled LDS, XCD swizzle) ----------------
// Single orientation acc[mt][nt] (row=t, col=channel) — r12 lesson: dual-orientation
// if(qk) in the K-loop -> 132 VGPR, occupancy 11%, +50us.
// q/k written scalar bf16 to QKV[0..1]; V written DIRECTLY TRANSPOSED to Vt_out[bh][d][t]
// (4 consecutive t at one d = one 8B store; replaces the transpose kernel).
__global__ __launch_bounds__(256) void gemm_qkv(const u16* __restrict__ A,
                                                const u16* __restrict__ B,
                                                const float* __restrict__ bias,
                                                u16* __restrict__ QKV,
                                                u16* __restrict__ Vt_out,
                                                int M, int N, int K) {
  __shared__ __align__(16) u16 As[128 * 64];
  __shared__ __align__(16) u16 Bs[128 * 64];
  const int tid = threadIdx.x;
  const int lane = tid & 63;
  const int wave = tid >> 6;
  const int quad = lane >> 4;
  const int l15 = lane & 15;

  // XCD-aware bijective remap (nwg % 8 == 0): XCD j serves a contiguous logical range
  const int nwg = gridDim.x * gridDim.y;
  int id = blockIdx.y * gridDim.x + blockIdx.x;
  id = (id & 7) * (nwg >> 3) + (id >> 3);
  const int bm0 = (id / gridDim.x) * 128;
  const int bn0 = (id % gridDim.x) * 128;

  const int wm = (wave & 1) * 64;
  const int wn = (wave >> 1) * 64;

  float4v acc[4][4];
#pragma unroll
  for (int i = 0; i < 4; ++i)
#pragma unroll
    for (int j = 0; j < 4; ++j) acc[i][j] = (float4v){0.f, 0.f, 0.f, 0.f};

  // staging with swizzled SOURCE column so LDS layout is chunk^row swizzled
  const int srow = wave * 32 + (lane >> 3);
  const int scol = ((lane & 7) ^ ((lane >> 3) & 7)) * 8;

  for (int k0 = 0; k0 < K; k0 += 64) {
#pragma unroll
    for (int s = 0; s < 4; ++s) {
      const int r = s * 8;
      load_lds_16(&A[(size_t)(bm0 + srow + r) * K + k0 + scol], &As[(wave * 32 + r) * 64]);
      load_lds_16(&B[(size_t)(bn0 + srow + r) * K + k0 + scol], &Bs[(wave * 32 + r) * 64]);
    }
    __builtin_amdgcn_s_waitcnt(0);
    __syncthreads();
#pragma unroll
    for (int ks = 0; ks < 2; ++ks) {
      short8 af[4], bf[4];
#pragma unroll
      for (int t = 0; t < 4; ++t) {
        af[t] = *(const short8*)&As[swz(wm + t * 16 + l15, ks * 32 + quad * 8)];
        bf[t] = *(const short8*)&Bs[swz(wn + t * 16 + l15, ks * 32 + quad * 8)];
      }
#pragma unroll
      for (int mt = 0; mt < 4; ++mt)
#pragma unroll
        for (int nt = 0; nt < 4; ++nt)
          acc[mt][nt] = MFMA16(af[mt], bf[nt], acc[mt][nt]);
    }
    __syncthreads();
  }

#pragma unroll
  for (int mt = 0; mt < 4; ++mt) {
    const int row0 = bm0 + wm + mt * 16 + quad * 4;
#pragma unroll
    for (int nt = 0; nt < 4; ++nt) {
      const int col = bn0 + wn + nt * 16 + l15;
      const float bs = bias[col];
      const int which = col >> 10;   // 0=q 1=k 2=v
      const int rem = col & 1023;
      const int h = rem >> 6;
      const int d = rem & 63;
      if (which == 2) {
        // V transposed: vt[(bh*64 + d)*2048 + t], 4 consecutive t -> one 8B store
        const int bb = row0 >> 11;
        const int tt0 = row0 & 2047;
        uint2 w;
        w.x = pack2(acc[mt][nt][0] + bs, acc[mt][nt][1] + bs);
        w.y = pack2(acc[mt][nt][2] + bs, acc[mt][nt][3] + bs);
        *(uint2*)&Vt_out[((size_t)(bb * 16 + h) * 64 + d) * 2048 + tt0] = w;
      } else {
        const float sc = (which == 0) ? Q_SCALE : 1.0f;  // pre-scale q for exp2 softmax
#pragma unroll
        for (int i = 0; i < 4; ++i) {
          const int t = row0 + i;
          const int b = t >> 11;
          const int tt = t & 2047;
          QKV[(size_t)which * 8388608 +
              ((size_t)(b * 16 + h) * 2048 + tt) * 64 + d] = f2b((acc[mt][nt][i] + bs) * sc);
        }
      }
    }
  }
}

// ---------------- GEMM2: 64x128 tiles, SWAPPED orientation -> float4 stores ----------------
// C[M,N] = A[M,K] * B[N,K]^T + bias, fp32 out. acc[nt][mt]: row = out-channel, col = t;
// thread holds 4 consecutive channels at one t -> one 16B float4 store.
// Single-path (no orientation branch) so register pressure stays flat (r12 lesson).
__global__ __launch_bounds__(256) void gemm2_64(const u16* __restrict__ A,
                                                const u16* __restrict__ B,
                                                const float* __restrict__ bias,
                                                float* __restrict__ Cf,
                                                int M, int N, int K) {
  __shared__ __align__(16) u16 As[64 * 64];
  __shared__ __align__(16) u16 Bs[128 * 64];
  const int tid = threadIdx.x;
  const int lane = tid & 63;
  const int wave = tid >> 6;
  const int quad = lane >> 4;
  const int l15 = lane & 15;

  // XCD-aware bijective remap (nwg % 8 == 0)
  const int nwg = gridDim.x * gridDim.y;
  int id = blockIdx.y * gridDim.x + blockIdx.x;
  id = (id & 7) * (nwg >> 3) + (id >> 3);
  const int bm0 = (id / gridDim.x) * 64;
  const int bn0 = (id % gridDim.x) * 128;

  const int wm = (wave & 1) * 32;
  const int wn = (wave >> 1) * 64;

  float4v acc[4][2];
#pragma unroll
  for (int i = 0; i < 4; ++i)
#pragma unroll
    for (int j = 0; j < 2; ++j) acc[i][j] = (float4v){0.f, 0.f, 0.f, 0.f};

  const int r8 = lane >> 3;
  const int c8 = ((lane & 7) ^ r8) * 8;

  for (int k0 = 0; k0 < K; k0 += 64) {
    // As: 64 rows = 8 chunks of 8 rows; c = wave*2+p
#pragma unroll
    for (int p = 0; p < 2; ++p) {
      const int c = wave * 2 + p;
      load_lds_16(&A[(size_t)(bm0 + c * 8 + r8) * K + k0 + c8], &As[c * 512]);
    }
    // Bs: 128 rows = 16 chunks; c = wave*4+p
#pragma unroll
    for (int p = 0; p < 4; ++p) {
      const int c = wave * 4 + p;
      load_lds_16(&B[(size_t)(bn0 + c * 8 + r8) * K + k0 + c8], &Bs[c * 512]);
    }
    __builtin_amdgcn_s_waitcnt(0);
    __syncthreads();
#pragma unroll
    for (int ks = 0; ks < 2; ++ks) {
      short8 af[2], bf[4];
#pragma unroll
      for (int t = 0; t < 2; ++t)
        af[t] = *(const short8*)&As[swz(wm + t * 16 + l15, ks * 32 + quad * 8)];
#pragma unroll
      for (int t = 0; t < 4; ++t)
        bf[t] = *(const short8*)&Bs[swz(wn + t * 16 + l15, ks * 32 + quad * 8)];
#pragma unroll
      for (int nt = 0; nt < 4; ++nt)
#pragma unroll
        for (int mt = 0; mt < 2; ++mt)
          acc[nt][mt] = MFMA16(bf[nt], af[mt], acc[nt][mt]);
    }
    __syncthreads();
  }

#pragma unroll
  for (int nt = 0; nt < 4; ++nt) {
    const int ch0 = bn0 + wn + nt * 16 + quad * 4;   // 4 consecutive out channels
    const float4 bsv = *(const float4*)&bias[ch0];
#pragma unroll
    for (int mt = 0; mt < 2; ++mt) {
      const int t = bm0 + wm + mt * 16 + l15;
      float4 w;
      w.x = acc[nt][mt][0] + bsv.x;
      w.y = acc[nt][mt][1] + bsv.y;
      w.z = acc[nt][mt][2] + bsv.z;
      w.w = acc[nt][mt][3] + bsv.w;
      *(float4*)&Cf[(size_t)t * N + ch0] = w;
    }
  }
}

// ---------------- flash attention: paired q-tiles, swapped QK^T, permlane softmax, ----------------
// ---------------- K 3-buf dist-2 + V 2-buf dist-1 in LDS, counted vmcnt, rs via ones-MFMA --------
// Grid (16, 64) with XCD-bijective remap: each XCD serves 8 complete bh's (K/V L2-local).
// Block handles q-tiles {bx, 31-bx}. LDS = 24KB K-ring + 16KB V-pingpong = 40KB.
// Stage order per iter: V(st+1) THEN K(st+2); end-of-iter vmcnt(2) drains V(st+1),K(st+1),
// keeps K(st+2) in flight. Never vmcnt(0) mid-loop.
// S^T = mfma(K, Q): lane holds P[q = l15][k = nt*16 + quad*4 + i]. P -> bf16 via pack2h
// (round-half-up, 5 ops vs 12 — attn is VALU-bound at 53% busy; P-pack was the largest chunk);
// permlane32+16 swaps assemble PV A-fragments in-register. Row-sums via MFMA(P, ones) land in
// o's C/D layout (no VALU adds, no epilogue shuffles).
__global__ __launch_bounds__(256) void attn_kernel(const u16* __restrict__ QKV,
                                                   const u16* __restrict__ Vt_g,
                                                   u16* __restrict__ Y) {
  int id = blockIdx.y * 16 + blockIdx.x;          // 0..1023
  id = (id & 7) * 128 + (id >> 3);                // bijective XCD remap
  const int bx = id & 15;   // 0..15
  const int bh = id >> 4;   // 0..63
  const int b = bh >> 4, h = bh & 15;
  const int tid = threadIdx.x;
  const int lane = tid & 63;
  const int wave = tid >> 6;
  const int quad = lane >> 4;
  const int l15 = lane & 15;
  const int qt[2] = {bx, 31 - bx};

  const u16* Qg = QKV + (size_t)bh * 2048 * 64;
  const u16* Kg = QKV + 8388608 + (size_t)bh * 2048 * 64;
  const u16* Vg = Vt_g + (size_t)bh * 64 * 2048;   // [d][t]

  __shared__ __align__(16) u16 Ks[3][64 * 64];
  __shared__ __align__(16) u16 Vt[2][64 * 64];

  // Q fragments (B-operand: n = q = l15, k-slot = quad*8+j); Q pre-scaled by GEMM1
  short8 qf[2][2];
#pragma unroll
  for (int u = 0; u < 2; ++u)
#pragma unroll
    for (int ks = 0; ks < 2; ++ks)
      qf[u][ks] = *(const short8*)&Qg[(size_t)(qt[u] * 64 + wave * 16 + l15) * 64 + ks * 32 + quad * 8];

  float4v o[2][4];
  float4v rsacc[2];
#pragma unroll
  for (int u = 0; u < 2; ++u) {
    rsacc[u] = (float4v){0.f, 0.f, 0.f, 0.f};
#pragma unroll
    for (int i = 0; i < 4; ++i) o[u][i] = (float4v){0.f, 0.f, 0.f, 0.f};
  }

  // bf16 ones vector for row-sum MFMA
  const short8 ones8 = {0x3F80, 0x3F80, 0x3F80, 0x3F80, 0x3F80, 0x3F80, 0x3F80, 0x3F80};

  // staging: swizzle the global SOURCE column chunk; LDS dest stays lane-linear
  const int r8 = lane >> 3;
  const int c8 = ((lane & 7) ^ r8) * 8;
  auto stageK = [&](int st_, int bufi) {
#pragma unroll
    for (int p = 0; p < 2; ++p) {
      const int c = wave * 2 + p;
      load_lds_16(&Kg[(size_t)(st_ * 64 + c * 8 + r8) * 64 + c8], &Ks[bufi][c * 512]);
    }
  };
  auto stageV = [&](int st_, int bufi) {
#pragma unroll
    for (int p = 0; p < 2; ++p) {
      const int c = wave * 2 + p;
      load_lds_16(&Vg[(size_t)(c * 8 + r8) * 2048 + st_ * 64 + c8], &Vt[bufi][c * 512]);
    }
  };

  const int last = qt[1];   // >= 16 always
  // prologue (issue order oldest->newest: V0, K0, K1)
  stageV(0, 0);
  stageK(0, 0);
  stageK(1, 1);
  asm volatile("s_waitcnt vmcnt(2)" ::: "memory");   // V0,K0 complete; K1 in flight
  __builtin_amdgcn_s_barrier();

  int cur = 0;
  for (int st = 0; st <= last; ++st) {
    const int vcur = st & 1;
    // issue V BEFORE K so vmcnt(2) at iter end drains V(st+1)
    if (st + 1 <= last) stageV(st + 1, vcur ^ 1);
    const bool pfk = (st + 2 <= last);      // block-uniform
    if (pfk) {
      int nb = cur + 2; if (nb >= 3) nb -= 3;
      stageK(st + 2, nb);                   // overwrites buffer read at iter st-1 (barrier-protected)
    }
    const bool both = (st <= qt[0]);        // block-uniform

    // S^T = K Q^T for both q-tiles, sharing each kf read
    float4v s[2][4];
#pragma unroll
    for (int u = 0; u < 2; ++u)
#pragma unroll
      for (int nt = 0; nt < 4; ++nt) s[u][nt] = (float4v){0.f, 0.f, 0.f, 0.f};
    __builtin_amdgcn_s_setprio(1);
#pragma unroll
    for (int ks = 0; ks < 2; ++ks)
#pragma unroll
      for (int nt = 0; nt < 4; ++nt) {
        const short8 kf = *(const short8*)&Ks[cur][swz(nt * 16 + l15, ks * 32 + quad * 8)];
        s[1][nt] = MFMA16(kf, qf[1][ks], s[1][nt]);
        if (both) s[0][nt] = MFMA16(kf, qf[0][ks], s[0][nt]);
      }
    __builtin_amdgcn_s_setprio(0);

    // softmax per q-tile -> PV A-fragments (pure VALU, no DS) + row-sum MFMA
    short8 af[2][2];
#pragma unroll
    for (int u = 0; u < 2; ++u) {
      if (u == 0 && !both) continue;

      if (st == qt[u]) {   // diagonal tile: causal mask (block-uniform branch)
        const int qrow = wave * 16 + l15;            // q local
        const int kb = quad * 4;                     // k local base
#pragma unroll
        for (int nt = 0; nt < 4; ++nt)
#pragma unroll
          for (int i = 0; i < 4; ++i)
            if (kb + nt * 16 + i > qrow) s[u][nt][i] = -1e30f;
      }

      // p = exp2(s); pack pairs to bf16 (round-half-up, cheap)
      unsigned pkx[4], pky[4];
#pragma unroll
      for (int nt = 0; nt < 4; ++nt) {
        const float p0 = __builtin_amdgcn_exp2f(s[u][nt][0]);
        const float p1 = __builtin_amdgcn_exp2f(s[u][nt][1]);
        const float p2 = __builtin_amdgcn_exp2f(s[u][nt][2]);
        const float p3 = __builtin_amdgcn_exp2f(s[u][nt][3]);
        pkx[nt] = pack2h(p0, p1);
        pky[nt] = pack2h(p2, p3);
      }

      // redistribute in-register: per ks, swap32 then swap16 on (pk[2ks], pk[2ks+1])
#pragma unroll
      for (int ks = 0; ks < 2; ++ks) {
        unsigned ax = pkx[2 * ks], bx2 = pkx[2 * ks + 1];
        unsigned ay = pky[2 * ks], by2 = pky[2 * ks + 1];
        asm("v_permlane32_swap_b32 %0, %1" : "+v"(ax), "+v"(bx2));
        asm("v_permlane16_swap_b32 %0, %1" : "+v"(ax), "+v"(bx2));
        asm("v_permlane32_swap_b32 %0, %1" : "+v"(ay), "+v"(by2));
        asm("v_permlane16_swap_b32 %0, %1" : "+v"(ay), "+v"(by2));
        uint4 w;
        w.x = ax; w.y = ay; w.z = bx2; w.w = by2;
        af[u][ks] = *(const short8*)&w;
        // row-sum in o's C/D layout: rsacc[u][i] = sum_k P[q = quad*4+i][k]
        rsacc[u] = MFMA16(af[u][ks], ones8, rsacc[u]);
      }
    }

    // O += P V, vf from LDS ping-pong, shared across both q-tiles
    __builtin_amdgcn_s_setprio(1);
#pragma unroll
    for (int ks = 0; ks < 2; ++ks)
#pragma unroll
      for (int dt = 0; dt < 4; ++dt) {
        const short8 vf = *(const short8*)&Vt[vcur][swz(dt * 16 + l15, ks * 32 + quad * 8)];
        o[1][dt] = MFMA16(af[1][ks], vf, o[1][dt]);
        if (both) o[0][dt] = MFMA16(af[0][ks], vf, o[0][dt]);
      }
    __builtin_amdgcn_s_setprio(0);

    // counted wait: V(st+1), K(st+1) complete; K(st+2)'s 2 loads stay in flight
    if (pfk) asm volatile("s_waitcnt vmcnt(2)" ::: "memory");
    else     asm volatile("s_waitcnt vmcnt(0)" ::: "memory");
    __builtin_amdgcn_s_barrier();

    ++cur; if (cur >= 3) cur = 0;
  }

  // epilogue: rsacc already in o's layout -> normalize directly, write Y[b][t][h*64+d]
#pragma unroll
  for (int u = 0; u < 2; ++u) {
    float linv[4];
#pragma unroll
    for (int i = 0; i < 4; ++i) linv[i] = 1.0f / rsacc[u][i];
#pragma unroll
    for (int dt = 0; dt < 4; ++dt)
#pragma unroll
      for (int i = 0; i < 4; ++i) {
        const float v = o[u][dt][i] * linv[i];
        const int t = qt[u] * 64 + wave * 16 + quad * 4 + i;
        Y[((size_t)b * 2048 + t) * 1024 + h * 64 + dt * 16 + l15] = f2b(v);
      }
  }
}

// ---------------- launch ----------------
extern "C" void kernel_launch(void* const* d_in, const int* in_sizes, int n_in,
                              void* d_out, int out_size, void* d_ws, size_t ws_size,
                              hipStream_t stream) {
  const float* x  = (const float*)d_in[0];   // [4,2048,1024]
  const float* Wa = (const float*)d_in[1];   // [3072,1024]
  const float* ba = (const float*)d_in[2];   // [3072]
  const float* Wp = (const float*)d_in[3];   // [1024,1024]
  const float* bp = (const float*)d_in[4];   // [1024]
  float* out = (float*)d_out;                // [4,2048,1024] fp32

  u16* xb  = (u16*)d_ws;                  // 8388608  (reused as Y after GEMM1)
  u16* Wab = xb + 8388608;                // 3145728
  u16* Wpb = Wab + 3145728;               // 1048576
  u16* qkv = Wpb + 1048576;               // q,k used; v slot unused (V goes transposed to vt)
  u16* y   = xb;                          // alias: x consumed by GEMM1 before attn writes y
  u16* vt  = (u16*)d_out;                 // 16.8MB scratch in d_out (GEMM2 overwrites later)

  cvt_all<<<6144, 256, 0, stream>>>(x, Wa, Wp, xb, Wab, Wpb);

  gemm_qkv<<<dim3(24, 64), 256, 0, stream>>>(xb, Wab, ba, qkv, vt, 8192, 3072, 1024);
  attn_kernel<<<dim3(16, 64), 256, 0, stream>>>(qkv, vt, y);
  gemm2_64<<<dim3(8, 128), 256, 0, stream>>>(y, Wpb, bp, out, 8192, 1024, 1024);
}